// Round 1
// baseline (124.166 us; speedup 1.0000x reference)
//
#include <hip/hip_runtime.h>
#include <math.h>

// QuanvolutionPlus round 5: MFMA matvec + trig-polynomial quantum features.
//
// vs round 4 (kernel ~27us, VALU-issue bound, MfmaUtil=0):
//  - block = 16 samples (4 waves, 1024 blocks). Feature phase writes cls
//    (conv+BN+ReLU, n-order c*196+p) and q (quantum, n-order 4p+j) as f16 rows
//    in LDS (FSTRIDE=808: 16B-aligned b128 reads, bank phase 20*row%32 -> 2-way).
//  - quantum circuit reduced to out = sum K[9] * {1,cA,sA}x{1,cB,sB} with
//    A=a11+a21 (full angle): everything after the encoding is a fixed linear
//    map U(v); out_f = e^T (U^T G_f U) e collapses via double-angle. 32 FMA +
//    2 sincos per patch vs ~66 ops. K (36 floats) + BN-folded conv weights are
//    computed by a 1-thread pre-kernel into d_ws -> uniform s_loads, ~0 VALU.
//  - matvec on the idle MFMA pipe: mfma_f32_16x16x32_f16, M=16 samples,
//    N=16 (10 classes + zero pad), K=800 (784 + zeroed pad), split 7/7/7/4
//    K-steps across the 4 waves. A-frag = cls8+q8 (fused add, 4 pk_add_f16);
//    B-frags (lin_w f16) preloaded to 28 VGPRs from global. Partials summed
//    via 4KB LDS aliased onto the consumed cls buffer; softmax per 16-lane
//    group via shfl_xor. Replaces 140 dot2 + 5-stage DPP reduce per wave.
//  - LDS 50.5KB -> 3 blocks/CU (12 waves/CU).
//
// Index facts (verified rounds 1-2): cls flat n = c*196+p ; q flat n = 4p+k ;
// logits[o] = sum_n fused[n]*lin_w[o*784+n] + lin_b[o]. MFMA layouts:
// A: row=lane&15, k=(lane>>4)*8+j (contiguous 8) ; B: col=lane&15, same k ;
// D: col=lane&15, row=(lane>>4)*4+reg (guide-verified).

typedef __fp16 h2 __attribute__((ext_vector_type(2)));
typedef __fp16 h4 __attribute__((ext_vector_type(4)));
typedef __fp16 h8 __attribute__((ext_vector_type(8)));
typedef float f32x4 __attribute__((ext_vector_type(4)));

#define NSAMP 16
#define FSTRIDE 808   // f16 elems/row: 784 data + 16 zeroed (k=784..799) + 8 slack

// ---------------------------------------------------------------------------
// Pre-kernel: BN-folded conv weights (ws[0..35]), conv bias (ws[36..39]),
// quantum polynomial coefficients (ws[40..75], 9 per feature).
// ---------------------------------------------------------------------------
__global__ void quanv_precomp(const float* __restrict__ conv_w,
                              const float* __restrict__ bn_gamma,
                              const float* __restrict__ bn_beta,
                              const float* __restrict__ bn_mean,
                              const float* __restrict__ bn_var,
                              const float* __restrict__ var_params,
                              float* __restrict__ ws)
{
    if (threadIdx.x != 0 || blockIdx.x != 0) return;

    #pragma unroll
    for (int c = 0; c < 4; ++c) {
        float iv = bn_gamma[c] * rsqrtf(bn_var[c] + 1e-5f);
        #pragma unroll
        for (int k = 0; k < 9; ++k) ws[c * 9 + k] = conv_w[c * 9 + k] * iv;
        ws[36 + c] = bn_beta[c] - bn_mean[c] * iv;
    }

    float cv[4], sv[4];
    #pragma unroll
    for (int k = 0; k < 4; ++k) __sincosf(var_params[k] * 0.5f, &sv[k], &cv[k]);

    // U = RY3(w1) RY2(w0) CNOT10 RY1(w1) RY0(w0) CNOT01 acting on e_{2j+k}
    // (e = vec of 2x2 state, j=wire0 row, k=wire1 col). Matches the inline
    // m/t/u/p/q chain of rounds 1-4.
    float U[4][4];
    #pragma unroll
    for (int col = 0; col < 4; ++col) {
        float v0 = (col == 0), v1 = (col == 1), v2 = (col == 2), v3 = (col == 3);
        float t;
        t = v2; v2 = v3; v3 = t;                                     // CNOT 0->1
        t = cv[0]*v0 - sv[0]*v2; v2 = sv[0]*v0 + cv[0]*v2; v0 = t;   // RY(v0) w0
        t = cv[0]*v1 - sv[0]*v3; v3 = sv[0]*v1 + cv[0]*v3; v1 = t;
        t = cv[1]*v0 - sv[1]*v1; v1 = sv[1]*v0 + cv[1]*v1; v0 = t;   // RY(v1) w1
        t = cv[1]*v2 - sv[1]*v3; v3 = sv[1]*v2 + cv[1]*v3; v2 = t;
        t = v1; v1 = v3; v3 = t;                                     // CNOT 1->0
        t = cv[2]*v0 - sv[2]*v2; v2 = sv[2]*v0 + cv[2]*v2; v0 = t;   // RY(v2) w0
        t = cv[2]*v1 - sv[2]*v3; v3 = sv[2]*v1 + cv[2]*v3; v1 = t;
        t = cv[3]*v0 - sv[3]*v1; v1 = sv[3]*v0 + cv[3]*v1; v0 = t;   // RY(v3) w1
        t = cv[3]*v2 - sv[3]*v3; v3 = sv[3]*v2 + cv[3]*v3; v2 = t;
        U[0][col] = v0; U[1][col] = v1; U[2][col] = v2; U[3][col] = v3;
    }

    // Per feature f: A = U^T G_f U ; then 9 coefficients over
    // {1,cA,sA} x {1,cB,sB} via double-angle (A=2ha, B=2hb).
    #pragma unroll
    for (int f = 0; f < 4; ++f) {
        float M[4][4];
        #pragma unroll
        for (int r = 0; r < 4; ++r) {
            int src = r; float sgn = 1.f;
            if      (f == 0) { sgn = (r < 2) ? 1.f : -1.f; }        // z0: diag(+,+,-,-)
            else if (f == 1) { sgn = ((r & 1) == 0) ? 1.f : -1.f; } // z1: diag(+,-,+,-)
            else if (f == 2) { src = r ^ 2; }                       // x0: rows [2,3,0,1]
            else             { src = r ^ 1; }                       // x1: rows [1,0,3,2]
            #pragma unroll
            for (int j = 0; j < 4; ++j) M[r][j] = sgn * U[src][j];
        }
        float A[4][4];
        #pragma unroll
        for (int i = 0; i < 4; ++i)
            #pragma unroll
            for (int j = 0; j < 4; ++j)
                A[i][j] = U[0][i]*M[0][j] + U[1][i]*M[1][j]
                        + U[2][i]*M[2][j] + U[3][i]*M[3][j];

        float a1 = 0.5f*(A[0][0]+A[1][1]), b1 = 0.5f*(A[0][0]-A[1][1]), g1 = 0.5f*(A[0][1]+A[1][0]);
        float a2 = 0.5f*(A[2][2]+A[3][3]), b2 = 0.5f*(A[2][2]-A[3][3]), g2 = 0.5f*(A[2][3]+A[3][2]);
        float u00 = A[0][2]+A[2][0], u01 = A[0][3]+A[2][1];
        float u10 = A[1][2]+A[3][0], u11 = A[1][3]+A[3][1];
        float a3 = 0.5f*(u00+u11), b3 = 0.5f*(u00-u11), g3 = 0.5f*(u01+u10);

        float* K = ws + 40 + 9 * f;
        K[0] = 0.5f*(a1+a2); K[1] = 0.5f*(a1-a2); K[2] = 0.5f*a3;   // 1,  cA, sA
        K[3] = 0.5f*(b1+b2); K[4] = 0.5f*(b1-b2); K[5] = 0.5f*b3;   // *cB
        K[6] = 0.5f*(g1+g2); K[7] = 0.5f*(g1-g2); K[8] = 0.5f*g3;   // *sB
    }
}

// ---------------------------------------------------------------------------
// Main kernel.
// ---------------------------------------------------------------------------
__global__ __launch_bounds__(256, 3)
void quanv_main(const float* __restrict__ x,
                const float* __restrict__ ws,
                const float* __restrict__ lin_w,
                const float* __restrict__ lin_b,
                float* __restrict__ out, int B)
{
    __shared__ __align__(16) __fp16 clsB[NSAMP * FSTRIDE]; // later aliased: float pw[4][16][16]
    __shared__ __align__(16) __fp16 qB[NSAMP * FSTRIDE];

    const int tid  = threadIdx.x;
    const int lane = tid & 63;
    const int wave = tid >> 6;

    // Zero the k=784..799 pad of both buffers (A operand must be non-NaN
    // even where B is zero). tid = r*16 + buf*8 + w covers all 16x2x8 dwords.
    {
        int r = tid >> 4, buf = (tid >> 3) & 1, w = tid & 7;
        int* wp = (int*)((buf ? qB : clsB) + r * FSTRIDE + 784);
        wp[w] = 0;
    }

    // ---- B fragments (lin_w -> f16) straight to registers, 7 K-steps/wave ----
    const int bcol = lane & 15, bkg = lane >> 4;
    const __fp16 hz = (__fp16)0.f;
    h8 bfrag[7];
    #pragma unroll
    for (int t = 0; t < 7; ++t) {
        int st = wave * 7 + t;
        int kb = st * 32 + bkg * 8;
        h8 bf = {hz, hz, hz, hz, hz, hz, hz, hz};
        if (bcol < 10 && kb < 784) {
            const float4* lw4 = (const float4*)(lin_w + bcol * 784 + kb);
            float4 v0 = lw4[0], v1 = lw4[1];
            h2 p0 = __builtin_amdgcn_cvt_pkrtz(v0.x, v0.y);
            h2 p1 = __builtin_amdgcn_cvt_pkrtz(v0.z, v0.w);
            h2 p2 = __builtin_amdgcn_cvt_pkrtz(v1.x, v1.y);
            h2 p3 = __builtin_amdgcn_cvt_pkrtz(v1.z, v1.w);
            h8 tv = {p0.x, p0.y, p1.x, p1.y, p2.x, p2.y, p3.x, p3.y};
            bf = tv;
        }
        bfrag[t] = bf;
    }

    // ---- feature phase: 16 consecutive tids = 16 patch columns of 1 sample ----
    const int s_loc = tid >> 4;    // sample in block
    const int pcol  = tid & 15;    // patch col base; p = pcol + 16*it
    const int sg    = blockIdx.x * NSAMP + s_loc;
    const int sgc   = (sg < B) ? sg : (B - 1);
    const float* xs = x + (size_t)sgc * 784;
    __fp16* clsRow  = clsB + s_loc * FSTRIDE;
    __fp16* qRow    = qB   + s_loc * FSTRIDE;

    #pragma unroll
    for (int it = 0; it < 13; ++it) {
        int p = pcol + 16 * it;
        p = (p < 196) ? p : 195;          // clamped dup writes same value: benign
        unsigned ii = (unsigned)p / 14u;
        int j  = p - (int)ii * 14;
        int om = (int)ii * 56 + 2 * j;    // element offset of x[2i][2j]

        // 6 aligned float2 loads; clamps keep addresses in [0,783]
        float2 Rm = *(const float2*)(xs + om);
        float2 Rb = *(const float2*)(xs + om + 28);
        int ot = om - 28;  ot  = (ot  > 0) ? ot  : 0;
        float2 Rt = *(const float2*)(xs + ot);
        int olt = om - 30; olt = (olt > 0) ? olt : 0;
        float2 Lt = *(const float2*)(xs + olt);
        int olm = om - 2;  olm = (olm > 0) ? olm : 0;
        float2 Lm = *(const float2*)(xs + olm);
        float2 Lb = *(const float2*)(xs + olm + 28);

        float mt = (ii > 0u) ? 1.f : 0.f;
        float ml = (j  > 0 ) ? 1.f : 0.f;
        float a00 = Lt.y * (mt * ml), a01 = Rt.x * mt, a02 = Rt.y * mt;
        float a10 = Lm.y * ml,        a11 = Rm.x,      a12 = Rm.y;
        float a20 = Lb.y * ml,        a21 = Rb.x,      a22 = Rb.y;

        // conv (BN folded into ws) + ReLU -> cls n-layout
        #pragma unroll
        for (int c = 0; c < 4; ++c) {
            float h = ws[36 + c];
            h = fmaf(ws[c*9+0], a00, h); h = fmaf(ws[c*9+1], a01, h);
            h = fmaf(ws[c*9+2], a02, h); h = fmaf(ws[c*9+3], a10, h);
            h = fmaf(ws[c*9+4], a11, h); h = fmaf(ws[c*9+5], a12, h);
            h = fmaf(ws[c*9+6], a20, h); h = fmaf(ws[c*9+7], a21, h);
            h = fmaf(ws[c*9+8], a22, h);
            clsRow[c * 196 + p] = (__fp16)fmaxf(h, 0.f);
        }

        // quantum via 9-term trig polynomial (A,B are FULL angles)
        float cA, sA, cB, sB;
        __sincosf(a11 + a21, &sA, &cA);
        __sincosf(a12 + a22, &sB, &cB);
        float o[4];
        #pragma unroll
        for (int f = 0; f < 4; ++f) {
            const float* k = ws + 40 + 9 * f;
            float t1 = fmaf(k[2], sA, fmaf(k[1], cA, k[0]));
            float t2 = fmaf(k[5], sA, fmaf(k[4], cA, k[3]));
            float t3 = fmaf(k[8], sA, fmaf(k[7], cA, k[6]));
            o[f] = fmaf(t3, sB, fmaf(t2, cB, t1));
        }
        h2 zz = __builtin_amdgcn_cvt_pkrtz(o[0], o[1]);
        h2 xx = __builtin_amdgcn_cvt_pkrtz(o[2], o[3]);
        h4 qv = {zz.x, zz.y, xx.x, xx.y};
        *(h4*)(qRow + 4 * p) = qv;
    }

    __syncthreads();   // (1) features visible to all waves

    // ---- MFMA matvec: wave w owns K-steps 7w..7w+6 (st<25 valid) ----
    f32x4 acc = {0.f, 0.f, 0.f, 0.f};
    {
        const int arow = lane & 15, akg = lane >> 4;
        #pragma unroll
        for (int t = 0; t < 7; ++t) {
            int st = wave * 7 + t;
            if (st < 25) {   // wave-uniform branch
                int off = arow * FSTRIDE + st * 32 + akg * 8;
                h8 a = *(const h8*)(clsB + off) + *(const h8*)(qB + off); // fused add
                acc = __builtin_amdgcn_mfma_f32_16x16x32_f16(a, bfrag[t], acc, 0, 0, 0);
            }
        }
    }

    __syncthreads();   // (2) all cls reads done -> safe to alias partials onto clsB
    float* pw = (float*)clsB;   // [4 waves][16 samples][16 classes]
    {
        const int col = lane & 15, rb = (lane >> 4) * 4;
        #pragma unroll
        for (int r = 0; r < 4; ++r)
            pw[(wave * 16 + rb + r) * 16 + col] = acc[r];
    }
    __syncthreads();   // (3) partials visible

    // ---- cross-wave sum + per-sample softmax (16 lanes per sample) ----
    {
        const int c = tid & 15;   // class; s_loc = tid>>4 is the sample
        float L = pw[s_loc * 16 + c] + pw[(16 + s_loc) * 16 + c]
                + pw[(32 + s_loc) * 16 + c] + pw[(48 + s_loc) * 16 + c];
        L = (c < 10) ? (L + lin_b[c]) : -1e30f;
        float mx = L;
        mx = fmaxf(mx, __shfl_xor(mx, 1, 16));
        mx = fmaxf(mx, __shfl_xor(mx, 2, 16));
        mx = fmaxf(mx, __shfl_xor(mx, 4, 16));
        mx = fmaxf(mx, __shfl_xor(mx, 8, 16));
        float se = (c < 10) ? __expf(L - mx) : 0.f;
        se += __shfl_xor(se, 1, 16);
        se += __shfl_xor(se, 2, 16);
        se += __shfl_xor(se, 4, 16);
        se += __shfl_xor(se, 8, 16);
        if (c < 10 && sg < B)
            out[(size_t)sg * 10 + c] = L - mx - __logf(se);
    }
}

extern "C" void kernel_launch(void* const* d_in, const int* in_sizes, int n_in,
                              void* d_out, int out_size, void* d_ws, size_t ws_size,
                              hipStream_t stream) {
    const float* x          = (const float*)d_in[0];
    const float* conv_w     = (const float*)d_in[1];
    const float* bn_gamma   = (const float*)d_in[2];
    const float* bn_beta    = (const float*)d_in[3];
    const float* bn_mean    = (const float*)d_in[4];
    const float* bn_var     = (const float*)d_in[5];
    const float* var_params = (const float*)d_in[6];
    const float* lin_w      = (const float*)d_in[7];
    const float* lin_b      = (const float*)d_in[8];
    float* out = (float*)d_out;
    float* ws  = (float*)d_ws;

    const int B = in_sizes[0] / 784;
    quanv_precomp<<<1, 64, 0, stream>>>(conv_w, bn_gamma, bn_beta, bn_mean,
                                        bn_var, var_params, ws);
    const int blocks = (B + NSAMP - 1) / NSAMP;
    quanv_main<<<blocks, 256, 0, stream>>>(x, ws, lin_w, lin_b, out, B);
}

// Round 2
// 110.785 us; speedup vs baseline: 1.1208x; 1.1208x over previous
//
#include <hip/hip_runtime.h>
#include <math.h>

// QuanvolutionPlus round 6: round-4 parallelism + MFMA matvec, single launch.
//
// Round-5 post-mortem (quanv_main 69.6us, VALUBusy 16%, MfmaUtil 0.2%, HBM 5%,
// Occ 25.5%): latency-bound. 16 threads/sample -> 1024 blocks -> 4096 waves
// TOTAL (4 waves of work per SIMD), 3 blocks/CU (51.7KB LDS), 13-iteration
// serialized load->use chains at 68 VGPRs. Nothing resident to hide latency.
// The separate 1-thread precomp launch also serialized ~10us on the stream,
// and the 9-coeff poly only pays for >=16 patches/thread.
//
// Round 6 design:
//  - 8 samples/block, 32 lanes/sample, 7 feature iters (round-4 geometry,
//    proven to hide latency): 2048 blocks = 8192 waves.
//  - inline quantum state evolution (round-4 verified chain); uniform params
//    inv/addc/cv/sv computed per-wave and forced to SGPRs via readfirstlane
//    (~60 ops once). conv_w stays s_loaded (uniform readonly). No precomp
//    kernel, no ws.
//  - matvec on the idle MFMA pipe: mfma_f32_16x16x32_f16, M=16 (rows 0-7 =
//    samples, rows 8-15 fed zeros - MFMA pipe is ~0% busy, half-waste is
//    free), N=16 (10 classes + pad), K=800 over 25 steps split 7/7/7/4
//    across waves. A-frag = cls8+q8 (fused add); B-frags in 28 VGPRs.
//    Replaces round-4's 140 dot2 + 5-stage DPP reduce per wave.
//  - LDS = cls[8][808] + q[8][808] f16 = 25.9KB -> 6 blocks/CU = 24 waves/CU.
//    A-read row stride 1616B -> bank phase 20*row: b128 reads conflict-free
//    (verified: rows 0-7 cover banks 0-31 exactly once per quarter-wave).
//  - partials (4 waves x 8 samples x 16) aliased onto clsB after barrier;
//    16-lane-group shfl_xor softmax.
//
// Index facts (verified rounds 1-5): cls flat n = c*196+p ; q flat n = 4p+k ;
// logits[o] = sum_n fused[n]*lin_w[o*784+n] + lin_b[o]. MFMA 16x16x32 f16:
// A row=lane&15, k=(lane>>4)*8+j ; B col=lane&15, same k ; D col=lane&15,
// row=(lane>>4)*4+reg (pass-verified in round 5).

typedef __fp16 h2 __attribute__((ext_vector_type(2)));
typedef __fp16 h4 __attribute__((ext_vector_type(4)));
typedef __fp16 h8 __attribute__((ext_vector_type(8)));
typedef float f32x4 __attribute__((ext_vector_type(4)));

#define NSAMP 8
#define FSTRIDE 808   // f16 elems/row: 784 data + 16 zeroed pad (k=784..799) + 8 slack

__device__ __forceinline__ float rfl(float v) {
    return __int_as_float(__builtin_amdgcn_readfirstlane(__float_as_int(v)));
}

__global__ __launch_bounds__(256, 6)
void quanv_fused(const float* __restrict__ x,
                 const float* __restrict__ conv_w,
                 const float* __restrict__ bn_gamma,
                 const float* __restrict__ bn_beta,
                 const float* __restrict__ bn_mean,
                 const float* __restrict__ bn_var,
                 const float* __restrict__ var_params,
                 const float* __restrict__ lin_w,
                 const float* __restrict__ lin_b,
                 float* __restrict__ out, int B)
{
    __shared__ __align__(16) __fp16 clsB[NSAMP * FSTRIDE]; // aliased later: float pw[4][8][16]
    __shared__ __align__(16) __fp16 qB[NSAMP * FSTRIDE];

    const int tid  = threadIdx.x;
    const int lane = tid & 63;
    const int wave = tid >> 6;

    // Zero the k=784..799 pad of both buffers (A operand must be clean where
    // B is zero). tid = r*16 + buf*8 + w covers 8 rows x 2 bufs x 8 dwords.
    if (tid < 128) {
        int r = tid >> 4, buf = (tid >> 3) & 1, w = tid & 7;
        int* wp = (int*)((buf ? qB : clsB) + r * FSTRIDE + 784);
        wp[w] = 0;
    }

    // ---- B fragments (lin_w -> f16) straight to registers, 7 K-steps/wave ----
    const int bcol = lane & 15, bkg = lane >> 4;
    const __fp16 hz = (__fp16)0.f;
    const h8 hz8 = {hz, hz, hz, hz, hz, hz, hz, hz};
    h8 bfrag[7];
    #pragma unroll
    for (int t = 0; t < 7; ++t) {
        int st = wave * 7 + t;
        int kb = st * 32 + bkg * 8;
        h8 bf = hz8;
        if (bcol < 10 && kb < 784) {
            const float4* lw4 = (const float4*)(lin_w + bcol * 784 + kb);
            float4 v0 = lw4[0], v1 = lw4[1];
            h2 p0 = __builtin_amdgcn_cvt_pkrtz(v0.x, v0.y);
            h2 p1 = __builtin_amdgcn_cvt_pkrtz(v0.z, v0.w);
            h2 p2 = __builtin_amdgcn_cvt_pkrtz(v1.x, v1.y);
            h2 p3 = __builtin_amdgcn_cvt_pkrtz(v1.z, v1.w);
            h8 tv = {p0.x, p0.y, p1.x, p1.y, p2.x, p2.y, p3.x, p3.y};
            bf = tv;
        }
        bfrag[t] = bf;
    }

    // ---- uniform small params; VALU-computed ones forced to SGPR via rfl ----
    float inv[4], addc[4];
    #pragma unroll
    for (int c = 0; c < 4; ++c) {
        float iv = bn_gamma[c] * rsqrtf(bn_var[c] + 1e-5f);
        inv[c]  = rfl(iv);
        addc[c] = rfl(bn_beta[c] - bn_mean[c] * iv);
    }
    float cv[4], sv[4];
    #pragma unroll
    for (int k = 0; k < 4; ++k) {
        float s, c;
        __sincosf(var_params[k] * 0.5f, &s, &c);
        sv[k] = rfl(s); cv[k] = rfl(c);
    }

    // ---- feature phase: 32 lanes per sample, 7 patch-iters ----
    const int s_loc = tid >> 5;    // sample in block (0..7)
    const int q32   = tid & 31;    // patch lane
    const int sg    = blockIdx.x * NSAMP + s_loc;
    const int sgc   = (sg < B) ? sg : (B - 1);
    const float* xs = x + (size_t)sgc * 784;
    __fp16* clsRow  = clsB + s_loc * FSTRIDE;
    __fp16* qRow    = qB   + s_loc * FSTRIDE;

    #pragma unroll
    for (int it = 0; it < 7; ++it) {
        int p = q32 + 32 * it;
        if (p < 196) {
            unsigned ii = (unsigned)p / 14u;
            int j  = p - (int)ii * 14;
            int om = (int)ii * 56 + 2 * j;    // element offset of x[2i][2j]

            // 6 aligned float2 loads; clamps keep addresses in [0,783]
            float2 Rm = *(const float2*)(xs + om);
            float2 Rb = *(const float2*)(xs + om + 28);
            int ot = om - 28;  ot  = (ot  > 0) ? ot  : 0;
            float2 Rt = *(const float2*)(xs + ot);
            int olt = om - 30; olt = (olt > 0) ? olt : 0;
            float2 Lt = *(const float2*)(xs + olt);
            int olm = om - 2;  olm = (olm > 0) ? olm : 0;
            float2 Lm = *(const float2*)(xs + olm);
            float2 Lb = *(const float2*)(xs + olm + 28);

            float mt = (ii > 0u) ? 1.f : 0.f;
            float ml = (j  > 0 ) ? 1.f : 0.f;
            float a00 = Lt.y * (mt * ml), a01 = Rt.x * mt, a02 = Rt.y * mt;
            float a10 = Lm.y * ml,        a11 = Rm.x,      a12 = Rm.y;
            float a20 = Lb.y * ml,        a21 = Rb.x,      a22 = Rb.y;

            // conv (s_loaded weights) + BN + ReLU -> cls n-layout
            #pragma unroll
            for (int c = 0; c < 4; ++c) {
                float h = conv_w[c*9+0]*a00 + conv_w[c*9+1]*a01 + conv_w[c*9+2]*a02
                        + conv_w[c*9+3]*a10 + conv_w[c*9+4]*a11 + conv_w[c*9+5]*a12
                        + conv_w[c*9+6]*a20 + conv_w[c*9+7]*a21 + conv_w[c*9+8]*a22;
                h = h * inv[c] + addc[c];
                clsRow[c * 196 + p] = (__fp16)fmaxf(h, 0.f);
            }

            // quantum state evolution (round-4 verified chain)
            float ha = 0.5f * (a11 + a21);
            float hb = 0.5f * (a12 + a22);
            float c0, s0, c1, s1;
            __sincosf(ha, &s0, &c0);
            __sincosf(hb, &s1, &c1);
            float m00 = c0*c1, m01 = c0*s1;
            float m10 = s0*s1, m11 = s0*c1;                                  // enc + CNOT(0->1)
            float t00 = cv[0]*m00 - sv[0]*m10, t01 = cv[0]*m01 - sv[0]*m11;
            float t10 = sv[0]*m00 + cv[0]*m10, t11 = sv[0]*m01 + cv[0]*m11;  // RY(v0) w0
            float u00 = cv[1]*t00 - sv[1]*t01, u01 = sv[1]*t00 + cv[1]*t01;
            float u10 = cv[1]*t10 - sv[1]*t11, u11 = sv[1]*t10 + cv[1]*t11;  // RY(v1) w1
            float tmp = u01; u01 = u11; u11 = tmp;                            // CNOT(1->0)
            float p00 = cv[2]*u00 - sv[2]*u10, p01 = cv[2]*u01 - sv[2]*u11;
            float p10 = sv[2]*u00 + cv[2]*u10, p11 = sv[2]*u01 + cv[2]*u11;  // RY(v2) w0
            float q00 = cv[3]*p00 - sv[3]*p01, q01 = sv[3]*p00 + cv[3]*p01;
            float q10 = cv[3]*p10 - sv[3]*p11, q11 = sv[3]*p10 + cv[3]*p11;  // RY(v3) w1

            float z0 = q00*q00 + q01*q01 - q10*q10 - q11*q11;
            float z1 = q00*q00 + q10*q10 - q01*q01 - q11*q11;
            float x0 = 2.f * (q00*q10 + q01*q11);
            float x1 = 2.f * (q00*q01 + q10*q11);
            h2 zz = __builtin_amdgcn_cvt_pkrtz(z0, z1);
            h2 xx = __builtin_amdgcn_cvt_pkrtz(x0, x1);
            h4 qv = {zz.x, zz.y, xx.x, xx.y};
            *(h4*)(qRow + 4 * p) = qv;
        }
    }

    __syncthreads();   // (1) features + pad zeros visible to all waves

    // ---- MFMA matvec: wave w owns K-steps 7w..7w+6 (st<25 valid) ----
    f32x4 acc = {0.f, 0.f, 0.f, 0.f};
    {
        const int arow = lane & 15, akg = lane >> 4;
        #pragma unroll
        for (int t = 0; t < 7; ++t) {
            int st = wave * 7 + t;
            if (st < 25) {   // wave-uniform branch
                h8 a = hz8;
                if (arow < NSAMP) {   // rows 8-15 feed zeros (M half-waste: free)
                    int off = arow * FSTRIDE + st * 32 + akg * 8;
                    a = *(const h8*)(clsB + off) + *(const h8*)(qB + off); // fused add
                }
                acc = __builtin_amdgcn_mfma_f32_16x16x32_f16(a, bfrag[t], acc, 0, 0, 0);
            }
        }
    }

    __syncthreads();   // (2) all cls reads done -> safe to alias partials onto clsB
    float* pw = (float*)clsB;   // [4 waves][8 samples][16 classes]
    if (lane < 32) {            // D rows 0..7 live in lanes 0..31
        const int col = lane & 15, rb = (lane >> 4) * 4;
        #pragma unroll
        for (int r = 0; r < 4; ++r)
            pw[(wave * 8 + rb + r) * 16 + col] = acc[r];
    }
    __syncthreads();   // (3) partials visible

    // ---- cross-wave sum + per-sample softmax (16 lanes per sample) ----
    if (tid < 128) {
        const int c  = tid & 15;   // class
        const int sl = tid >> 4;   // sample in block (0..7)
        float L = pw[sl * 16 + c] + pw[(8 + sl) * 16 + c]
                + pw[(16 + sl) * 16 + c] + pw[(24 + sl) * 16 + c];
        L = (c < 10) ? (L + lin_b[c]) : -1e30f;
        float mx = L;
        mx = fmaxf(mx, __shfl_xor(mx, 1, 16));
        mx = fmaxf(mx, __shfl_xor(mx, 2, 16));
        mx = fmaxf(mx, __shfl_xor(mx, 4, 16));
        mx = fmaxf(mx, __shfl_xor(mx, 8, 16));
        float se = (c < 10) ? __expf(L - mx) : 0.f;
        se += __shfl_xor(se, 1, 16);
        se += __shfl_xor(se, 2, 16);
        se += __shfl_xor(se, 4, 16);
        se += __shfl_xor(se, 8, 16);
        const int sg2 = blockIdx.x * NSAMP + sl;
        if (c < 10 && sg2 < B)
            out[(size_t)sg2 * 10 + c] = L - mx - __logf(se);
    }
}

extern "C" void kernel_launch(void* const* d_in, const int* in_sizes, int n_in,
                              void* d_out, int out_size, void* d_ws, size_t ws_size,
                              hipStream_t stream) {
    const float* x          = (const float*)d_in[0];
    const float* conv_w     = (const float*)d_in[1];
    const float* bn_gamma   = (const float*)d_in[2];
    const float* bn_beta    = (const float*)d_in[3];
    const float* bn_mean    = (const float*)d_in[4];
    const float* bn_var     = (const float*)d_in[5];
    const float* var_params = (const float*)d_in[6];
    const float* lin_w      = (const float*)d_in[7];
    const float* lin_b      = (const float*)d_in[8];
    float* out = (float*)d_out;

    const int B = in_sizes[0] / 784;
    const int blocks = (B + NSAMP - 1) / NSAMP;
    quanv_fused<<<blocks, 256, 0, stream>>>(x, conv_w, bn_gamma, bn_beta, bn_mean,
                                            bn_var, var_params, lin_w, lin_b, out, B);
}